// Round 1
// baseline (164.720 us; speedup 1.0000x reference)
//
#include <hip/hip_runtime.h>
#include <math.h>

#define B 256
#define M 64
#define SPLIT 8
#define ROWS_PER_BLOCK 512   // 4096 rt-rows per batch / SPLIT

__device__ __forceinline__ float wave_sum64(float v) {
    #pragma unroll
    for (int m = 32; m >= 1; m >>= 1) v += __shfl_xor(v, m);
    return v;
}

// K1: per (batch, split) block: partial prev_info[f] = sum_{rt} role[rt]*mem[b][rt][f]
//     and partial sum-of-squares of mem.
__global__ __launch_bounds__(256) void k_partial(
    const float* __restrict__ mem, const float* __restrict__ role1,
    const float* __restrict__ role2, float* __restrict__ prev_part,
    float* __restrict__ ss_part)
{
    const int b   = blockIdx.x / SPLIT;
    const int sp  = blockIdx.x % SPLIT;
    const int tid = threadIdx.x;
    const int row0 = sp * ROWS_PER_BLOCK;

    __shared__ float  role_s[ROWS_PER_BLOCK];
    __shared__ float4 part[4][16];
    __shared__ float  ss_lds[4];

    for (int i = tid; i < ROWS_PER_BLOCK; i += 256) {
        const int rt = row0 + i;
        role_s[i] = role1[b * M + (rt >> 6)] * role2[b * M + (rt & 63)];
    }
    __syncthreads();

    const float4* mem4 = (const float4*)(mem + (size_t)b * (M * M * M));
    const int f4   = tid & 15;   // which float4 of the 64-wide f dimension
    const int rsub = tid >> 4;   // 0..15 row-within-group

    float4 ap = make_float4(0.f, 0.f, 0.f, 0.f);
    float  ss = 0.f;
    #pragma unroll 8
    for (int i = 0; i < ROWS_PER_BLOCK / 16; ++i) {
        const int lrt = rsub + i * 16;
        const float4 v = mem4[(size_t)(row0 + lrt) * 16 + f4];
        const float  r = role_s[lrt];
        ap.x = fmaf(r, v.x, ap.x);
        ap.y = fmaf(r, v.y, ap.y);
        ap.z = fmaf(r, v.z, ap.z);
        ap.w = fmaf(r, v.w, ap.w);
        ss = fmaf(v.x, v.x, ss);
        ss = fmaf(v.y, v.y, ss);
        ss = fmaf(v.z, v.z, ss);
        ss = fmaf(v.w, v.w, ss);
    }

    // lanes l, l^16, l^32 (within a 64-wide wave) share the same f4 -> butterfly
    #pragma unroll
    for (int m = 16; m <= 32; m <<= 1) {
        ap.x += __shfl_xor(ap.x, m);
        ap.y += __shfl_xor(ap.y, m);
        ap.z += __shfl_xor(ap.z, m);
        ap.w += __shfl_xor(ap.w, m);
    }
    const float ssw = wave_sum64(ss);

    const int wave = tid >> 6;
    const int lane = tid & 63;
    if (lane < 16) part[wave][lane] = ap;
    if (lane == 0) ss_lds[wave] = ssw;
    __syncthreads();

    if (tid < 16) {
        float4 a0 = part[0][tid], a1 = part[1][tid], a2 = part[2][tid], a3 = part[3][tid];
        float4 s;
        s.x = (a0.x + a1.x) + (a2.x + a3.x);
        s.y = (a0.y + a1.y) + (a2.y + a3.y);
        s.z = (a0.z + a1.z) + (a2.z + a3.z);
        s.w = (a0.w + a1.w) + (a2.w + a3.w);
        ((float4*)prev_part)[(size_t)(b * SPLIT + sp) * 16 + tid] = s;
    }
    if (tid == 0)
        ss_part[b * SPLIT + sp] = (ss_lds[0] + ss_lds[1]) + (ss_lds[2] + ss_lds[3]);
}

// K2: per batch (64 threads): combine partials, gate, cur_info, analytic norm.
__global__ __launch_bounds__(64) void k_finalize(
    const float* __restrict__ prev_part, const float* __restrict__ ss_part,
    const float* __restrict__ hidden, const float* __restrict__ W_gate,
    const float* __restrict__ b_gate, const float* __restrict__ role1,
    const float* __restrict__ role2, const float* __restrict__ filer,
    float* __restrict__ c2, float* __restrict__ inv_norm)
{
    const int b    = blockIdx.x;
    const int lane = threadIdx.x;

    float p = 0.f;
    #pragma unroll
    for (int s = 0; s < SPLIT; ++s) p += prev_part[(size_t)(b * SPLIT + s) * M + lane];

    float ssm = 0.f;
    #pragma unroll
    for (int s = 0; s < SPLIT; ++s) ssm += ss_part[b * SPLIT + s];

    // write gate: sigmoid(h . W + bias + 1)
    float g = 0.f;
    #pragma unroll
    for (int j = 0; j < 8; ++j) {
        const int i = lane + j * 64;
        g = fmaf(hidden[(size_t)b * 512 + i], W_gate[i], g);
    }
    g = wave_sum64(g);
    g = 1.f / (1.f + expf(-(g + b_gate[0] + 1.f)));

    const float fil = filer[b * M + lane];
    const float cur = g * (fil - p);

    const float d1   = wave_sum64(p * cur);
    const float ssc  = wave_sum64(cur * cur);
    const float r1   = role1[b * M + lane];
    const float r2   = role2[b * M + lane];
    const float ssr1 = wave_sum64(r1 * r1);
    const float ssr2 = wave_sum64(r2 * r2);

    const float sc = 1.0f / (float)M;
    // ||new||^2 = ||mem||^2 + 2*sc*(prev . cur) + sc^2 * ||r1||^2 ||r2||^2 ||cur||^2
    const float ns  = ssm + 2.f * sc * d1 + sc * sc * ssr1 * ssr2 * ssc;
    const float nrm = fmaxf(sqrtf(ns), 1.0f);   // relu(n-1)+1 == max(n,1)
    const float inv = 1.0f / nrm;

    c2[b * M + lane] = cur * sc * inv;
    if (lane == 0) inv_norm[b] = inv;
}

// K3: out = mem * inv_norm[b] + role1[r]*role2[t] * c2[b][f]
__global__ __launch_bounds__(256) void k_write(
    const float* __restrict__ mem, const float* __restrict__ role1,
    const float* __restrict__ role2, const float* __restrict__ c2,
    const float* __restrict__ inv_norm, float* __restrict__ out)
{
    const float4* mem4 = (const float4*)mem;
    const float4* c2_4 = (const float4*)c2;
    float4* out4 = (float4*)out;
    const int total4 = B * (M * M * M / 4);   // 16,777,216
    const int stride = gridDim.x * blockDim.x;
    for (int idx = blockIdx.x * blockDim.x + threadIdx.x; idx < total4; idx += stride) {
        const int b   = idx >> 16;          // 65536 float4 per batch
        const int rem = idx & 65535;
        const int row = rem >> 4;           // rt in [0,4096)
        const int f4  = rem & 15;
        const int r = row >> 6, t = row & 63;
        const float rr  = role1[b * M + r] * role2[b * M + t];
        const float inv = inv_norm[b];
        const float4 v = mem4[idx];
        const float4 c = c2_4[b * 16 + f4];
        float4 o;
        o.x = fmaf(rr, c.x, v.x * inv);
        o.y = fmaf(rr, c.y, v.y * inv);
        o.z = fmaf(rr, c.z, v.z * inv);
        o.w = fmaf(rr, c.w, v.w * inv);
        out4[idx] = o;
    }
}

extern "C" void kernel_launch(void* const* d_in, const int* in_sizes, int n_in,
                              void* d_out, int out_size, void* d_ws, size_t ws_size,
                              hipStream_t stream) {
    const float* mem    = (const float*)d_in[0];
    const float* hidden = (const float*)d_in[1];
    const float* role1  = (const float*)d_in[2];
    const float* role2  = (const float*)d_in[3];
    const float* filer  = (const float*)d_in[4];
    const float* Wg     = (const float*)d_in[5];
    const float* bg     = (const float*)d_in[6];
    float* out = (float*)d_out;

    float* ws        = (float*)d_ws;
    float* prev_part = ws;            // B*SPLIT*M      = 131072 floats
    float* ss_part   = ws + 131072;   // B*SPLIT        =   2048 floats
    float* c2        = ws + 133120;   // B*M            =  16384 floats (16B-aligned)
    float* inv_n     = ws + 149504;   // B              =    256 floats

    hipLaunchKernelGGL(k_partial, dim3(B * SPLIT), dim3(256), 0, stream,
                       mem, role1, role2, prev_part, ss_part);
    hipLaunchKernelGGL(k_finalize, dim3(B), dim3(64), 0, stream,
                       prev_part, ss_part, hidden, Wg, bg, role1, role2, filer, c2, inv_n);
    hipLaunchKernelGGL(k_write, dim3(2048), dim3(256), 0, stream,
                       mem, role1, role2, c2, inv_n, out);
}

// Round 3
// 132.883 us; speedup vs baseline: 1.2396x; 1.2396x over previous
//
#include <hip/hip_runtime.h>
#include <math.h>

#define B 256
#define M 64
#define THREADS 1024
#define F4_PER_BATCH 65536   // 64*64*64/4
#define ITERS 64             // F4_PER_BATCH / THREADS

typedef float f32x4 __attribute__((ext_vector_type(4)));

__device__ __forceinline__ float wave_sum64(float v) {
    #pragma unroll
    for (int m = 32; m >= 1; m >>= 1) v += __shfl_xor(v, m);
    return v;
}

// One block per batch. Pass 1: reduce prev_info[f] and sum(mem^2) over the
// 1 MiB batch slice (fills L2/L3). Finalize in-block (gate, cur, analytic
// norm). Pass 2: re-read slice (L3-hot) and write out with nontemporal
// stores so the output stream doesn't evict the slice we're re-reading.
__global__ __launch_bounds__(THREADS) void k_fused(
    const float* __restrict__ mem, const float* __restrict__ hidden,
    const float* __restrict__ role1, const float* __restrict__ role2,
    const float* __restrict__ filer, const float* __restrict__ W_gate,
    const float* __restrict__ b_gate, float* __restrict__ out)
{
    const int b   = blockIdx.x;
    const int tid = threadIdx.x;

    __shared__ float role_s[M * M];      // 16 KiB: role1[r]*role2[t]
    __shared__ float part[16][M];        // per-wave prev_info partials
    __shared__ float ss_lds[16];
    __shared__ float c2_s[M];
    __shared__ float inv_s;

    #pragma unroll
    for (int i = tid; i < M * M; i += THREADS)
        role_s[i] = role1[b * M + (i >> 6)] * role2[b * M + (i & 63)];
    __syncthreads();

    const float4* mem4 = (const float4*)(mem + (size_t)b * (M * M * M));

    // ---- pass 1: prev_info + sum of squares ----
    float4 ap = make_float4(0.f, 0.f, 0.f, 0.f);
    float  ss = 0.f;
    #pragma unroll 8
    for (int i = 0; i < ITERS; ++i) {
        const int idx = i * THREADS + tid;
        const float4 v = mem4[idx];
        const float  r = role_s[idx >> 4];
        ap.x = fmaf(r, v.x, ap.x);
        ap.y = fmaf(r, v.y, ap.y);
        ap.z = fmaf(r, v.z, ap.z);
        ap.w = fmaf(r, v.w, ap.w);
        ss = fmaf(v.x, v.x, ss);
        ss = fmaf(v.y, v.y, ss);
        ss = fmaf(v.z, v.z, ss);
        ss = fmaf(v.w, v.w, ss);
    }

    // lanes l, l^16, l^32 share the same f4 (THREADS % 16 == 0)
    #pragma unroll
    for (int m = 16; m <= 32; m <<= 1) {
        ap.x += __shfl_xor(ap.x, m);
        ap.y += __shfl_xor(ap.y, m);
        ap.z += __shfl_xor(ap.z, m);
        ap.w += __shfl_xor(ap.w, m);
    }
    const float ssw = wave_sum64(ss);

    const int wave = tid >> 6;
    const int lane = tid & 63;
    if (lane < 16) {
        part[wave][4 * lane + 0] = ap.x;
        part[wave][4 * lane + 1] = ap.y;
        part[wave][4 * lane + 2] = ap.z;
        part[wave][4 * lane + 3] = ap.w;
    }
    if (lane == 0) ss_lds[wave] = ssw;
    __syncthreads();

    // ---- finalize (first wave) ----
    if (tid < M) {
        const int f = tid;
        float p = 0.f;
        #pragma unroll
        for (int w = 0; w < 16; ++w) p += part[w][f];
        float ssm = 0.f;
        #pragma unroll
        for (int w = 0; w < 16; ++w) ssm += ss_lds[w];

        float g = 0.f;
        #pragma unroll
        for (int j = 0; j < 8; ++j) {
            const int i = f + j * 64;
            g = fmaf(hidden[(size_t)b * 512 + i], W_gate[i], g);
        }
        g = wave_sum64(g);
        g = 1.f / (1.f + expf(-(g + b_gate[0] + 1.f)));

        const float fil = filer[b * M + f];
        const float cur = g * (fil - p);

        const float d1   = wave_sum64(p * cur);
        const float ssc  = wave_sum64(cur * cur);
        const float r1   = role1[b * M + f];
        const float r2   = role2[b * M + f];
        const float ssr1 = wave_sum64(r1 * r1);
        const float ssr2 = wave_sum64(r2 * r2);

        const float sc = 1.0f / (float)M;
        const float ns = ssm + 2.f * sc * d1 + sc * sc * ssr1 * ssr2 * ssc;
        const float inv = 1.0f / fmaxf(sqrtf(ns), 1.0f);

        c2_s[f] = cur * sc * inv;
        if (f == 0) inv_s = inv;
    }
    __syncthreads();

    // ---- pass 2: write out = mem*inv + role*c2 (slice should be L3-hot) ----
    const float  inv = inv_s;
    const float4 c   = ((const float4*)c2_s)[tid & 15];
    f32x4* out4 = (f32x4*)(out + (size_t)b * (M * M * M));
    #pragma unroll 8
    for (int i = 0; i < ITERS; ++i) {
        const int idx = i * THREADS + tid;
        const float4 v = mem4[idx];
        const float  r = role_s[idx >> 4];
        f32x4 o;
        o.x = fmaf(r, c.x, v.x * inv);
        o.y = fmaf(r, c.y, v.y * inv);
        o.z = fmaf(r, c.z, v.z * inv);
        o.w = fmaf(r, c.w, v.w * inv);
        __builtin_nontemporal_store(o, &out4[idx]);
    }
}

extern "C" void kernel_launch(void* const* d_in, const int* in_sizes, int n_in,
                              void* d_out, int out_size, void* d_ws, size_t ws_size,
                              hipStream_t stream) {
    const float* mem    = (const float*)d_in[0];
    const float* hidden = (const float*)d_in[1];
    const float* role1  = (const float*)d_in[2];
    const float* role2  = (const float*)d_in[3];
    const float* filer  = (const float*)d_in[4];
    const float* Wg     = (const float*)d_in[5];
    const float* bg     = (const float*)d_in[6];
    float* out = (float*)d_out;

    hipLaunchKernelGGL(k_fused, dim3(B), dim3(THREADS), 0, stream,
                       mem, hidden, role1, role2, filer, Wg, bg, out);
}